// Round 9
// baseline (298.376 us; speedup 1.0000x reference)
//
#include <hip/hip_runtime.h>
#include <hip/hip_cooperative_groups.h>
#include <math.h>

// Problem geometry (fixed by reference):
//   x: [B=16, C=256, 128, 128] fp32 ; H = 16 ; spatial N = 16384
#define BATCH 16
#define CH    256
#define HID   16
#define SPAT  16384            // 128*128
#define NPLANE (BATCH * CH)    // 4096 planes, 64 KiB fp32 each

typedef float vfloat4 __attribute__((ext_vector_type(4)));

// 256 blocks x 512 threads (8 waves). Each wave owns 2 planes; each plane is
// 64 float4-iters per lane:
//   iters 0..39  -> registers (40*2 dwords * 2 planes = 160 dwords/thread)
//   iters 40..58 -> LDS       (19*2*2 dwords * 512 thr * 4B = 155,648 B)
//   iters 59..63 -> tail, re-read in phase 3 (20.5 MB total, L3-hot)
#define IT_REG  40
#define IT_LDS  19
#define IT_HOLD (IT_REG + IT_LDS)   // 59
#define IT_TOT  64

namespace cg = cooperative_groups;

// bf16 round-to-nearest-even, plain integer ops (finite inputs only)
__device__ __forceinline__ unsigned short f2bf(float f) {
    unsigned int u = __builtin_bit_cast(unsigned int, f);
    u += 0x7fffu + ((u >> 16) & 1u);
    return (unsigned short)(u >> 16);
}
__device__ __forceinline__ float bf2f(unsigned short h) {
    unsigned int u = ((unsigned int)h) << 16;
    return __builtin_bit_cast(float, u);
}
__device__ __forceinline__ unsigned pack_bf2(float a, float b) {
    return (unsigned)f2bf(a) | ((unsigned)f2bf(b) << 16);
}
__device__ __forceinline__ vfloat4 unpack2(unsigned u0, unsigned u1, float m) {
    vfloat4 v;
    v.x = bf2f((unsigned short)(u0 & 0xffffu)) * m;
    v.y = bf2f((unsigned short)(u0 >> 16))     * m;
    v.z = bf2f((unsigned short)(u1 & 0xffffu)) * m;
    v.w = bf2f((unsigned short)(u1 >> 16))     * m;
    return v;
}

// ---------------------------------------------------------------------------
// Cooperative persistent kernel: 256 blocks x 512 threads, 1 block/CU.
// __launch_bounds__(512, 1): R6 showed (1024,4)->64 VGPR and R8 showed
// (512,2)->128 VGPR, i.e. the 2nd arg behaves as min BLOCKS/CU; (512,1)
// -> 2 waves/EU -> 256-VGPR cap, enough for the 160-dword retention array.
// ---------------------------------------------------------------------------
__global__ __launch_bounds__(512, 1) void coop_kernel(
    const float* __restrict__ x,
    const float* __restrict__ sw1, const float* __restrict__ sb1,
    const float* __restrict__ sw2, const float* __restrict__ sb2,
    const float* __restrict__ mw1, const float* __restrict__ mb1,
    const float* __restrict__ mw2, const float* __restrict__ mb2,
    const float* __restrict__ bw,  const float* __restrict__ bb,
    const float* __restrict__ fw1, const float* __restrict__ fb1,
    const float* __restrict__ fw2, const float* __restrict__ fb2,
    float* __restrict__ out,
    float* __restrict__ mean_g, float* __restrict__ std_g)
{
    __shared__ unsigned lds_data[2 * IT_LDS * 1024];  // 155,648 B retained bf16
    __shared__ float s_desc[2 * CH];                  // SE scratch (5,248 B)
    __shared__ float s_h[HID];
    __shared__ float s_fused[2 * CH];
    __shared__ float s_g[CH];
    __shared__ float s_mask[16];

    const int tid  = threadIdx.x;
    const int w    = tid >> 6;          // wave 0..7
    const int lane = tid & 63;
    const int planeA = blockIdx.x * 16 + 2 * w;       // global (b,c) planes
    const int planeB = planeA + 1;

    const vfloat4* pA = reinterpret_cast<const vfloat4*>(x + (long long)planeA * SPAT);
    const vfloat4* pB = reinterpret_cast<const vfloat4*>(x + (long long)planeB * SPAT);

    unsigned rA[2 * IT_REG];
    unsigned rB[2 * IT_REG];

    // ---------------- Phase 1: stats + bf16 retention ----------------
    float sA = 0.f, s2A = 0.f, sB = 0.f, s2B = 0.f;

    // Retained portion: NON-TEMPORAL loads (no reuse from cache; keep L3 clean
    // for the tail). Tail portion: CACHED loads, read LAST -> L3-hot at phase 3.
    #pragma unroll
    for (int i = 0; i < IT_REG; ++i) {
        const vfloat4 v = __builtin_nontemporal_load(&pA[lane + i * 64]);
        sA  += (v.x + v.y) + (v.z + v.w);
        s2A  = fmaf(v.x, v.x, fmaf(v.y, v.y, fmaf(v.z, v.z, fmaf(v.w, v.w, s2A))));
        rA[2 * i]     = pack_bf2(v.x, v.y);
        rA[2 * i + 1] = pack_bf2(v.z, v.w);
    }
    #pragma unroll
    for (int i = 0; i < IT_LDS; ++i) {
        const vfloat4 v = __builtin_nontemporal_load(&pA[lane + (IT_REG + i) * 64]);
        sA  += (v.x + v.y) + (v.z + v.w);
        s2A  = fmaf(v.x, v.x, fmaf(v.y, v.y, fmaf(v.z, v.z, fmaf(v.w, v.w, s2A))));
        uint2 u; u.x = pack_bf2(v.x, v.y); u.y = pack_bf2(v.z, v.w);
        *reinterpret_cast<uint2*>(&lds_data[(0 * IT_LDS + i) * 1024 + tid * 2]) = u;
    }
    #pragma unroll
    for (int i = 0; i < IT_REG; ++i) {
        const vfloat4 v = __builtin_nontemporal_load(&pB[lane + i * 64]);
        sB  += (v.x + v.y) + (v.z + v.w);
        s2B  = fmaf(v.x, v.x, fmaf(v.y, v.y, fmaf(v.z, v.z, fmaf(v.w, v.w, s2B))));
        rB[2 * i]     = pack_bf2(v.x, v.y);
        rB[2 * i + 1] = pack_bf2(v.z, v.w);
    }
    #pragma unroll
    for (int i = 0; i < IT_LDS; ++i) {
        const vfloat4 v = __builtin_nontemporal_load(&pB[lane + (IT_REG + i) * 64]);
        sB  += (v.x + v.y) + (v.z + v.w);
        s2B  = fmaf(v.x, v.x, fmaf(v.y, v.y, fmaf(v.z, v.z, fmaf(v.w, v.w, s2B))));
        uint2 u; u.x = pack_bf2(v.x, v.y); u.y = pack_bf2(v.z, v.w);
        *reinterpret_cast<uint2*>(&lds_data[(1 * IT_LDS + i) * 1024 + tid * 2]) = u;
    }
    // Tail: cached loads, read last.
    #pragma unroll
    for (int i = IT_HOLD; i < IT_TOT; ++i) {
        const vfloat4 v = pA[lane + i * 64];
        sA  += (v.x + v.y) + (v.z + v.w);
        s2A  = fmaf(v.x, v.x, fmaf(v.y, v.y, fmaf(v.z, v.z, fmaf(v.w, v.w, s2A))));
    }
    #pragma unroll
    for (int i = IT_HOLD; i < IT_TOT; ++i) {
        const vfloat4 v = pB[lane + i * 64];
        sB  += (v.x + v.y) + (v.z + v.w);
        s2B  = fmaf(v.x, v.x, fmaf(v.y, v.y, fmaf(v.z, v.z, fmaf(v.w, v.w, s2B))));
    }

    // wave64 butterfly reduce; lane 0 publishes plane stats
    #pragma unroll
    for (int off = 32; off > 0; off >>= 1) {
        sA  += __shfl_xor(sA,  off);
        s2A += __shfl_xor(s2A, off);
        sB  += __shfl_xor(sB,  off);
        s2B += __shfl_xor(s2B, off);
    }
    if (lane == 0) {
        const float mA   = sA * (1.f / SPAT);
        const float varA = s2A * (1.f / SPAT) - mA * mA;
        mean_g[planeA] = mA;
        std_g[planeA]  = sqrtf(fmaxf(varA, 0.f));
        const float mB   = sB * (1.f / SPAT);
        const float varB = s2B * (1.f / SPAT) - mB * mB;
        mean_g[planeB] = mB;
        std_g[planeB]  = sqrtf(fmaxf(varB, 0.f));
    }

    cg::this_grid().sync();

    // ---------------- Phase 2: SE chain for this block's batch row ----------
    const int brow = blockIdx.x >> 4;     // 16 blocks share a batch row
    if (tid < CH) {
        s_desc[tid]      = std_g [brow * CH + tid];
        s_desc[CH + tid] = mean_g[brow * CH + tid];
    }
    __syncthreads();

    auto se_l1 = [&](const float* desc, const float* __restrict__ w1,
                     const float* __restrict__ b1) {
        if (tid < 256) {
            const int hh = tid >> 4;
            const int j  = tid & 15;
            float acc = 0.f;
            #pragma unroll
            for (int k = 0; k < 16; ++k) {
                const int c = j * 16 + k;
                acc += desc[c] * w1[hh * CH + c];
            }
            #pragma unroll
            for (int off = 1; off < 16; off <<= 1)
                acc += __shfl_xor(acc, off, 16);
            if (j == 0) s_h[hh] = fmaxf(acc + b1[hh], 0.f);
        }
    };
    auto se_l2 = [&](const float* __restrict__ w2, const float* __restrict__ b2,
                     float* outbuf) {
        if (tid < 256) {
            float acc = b2[tid];
            const vfloat4* w4 = reinterpret_cast<const vfloat4*>(w2 + tid * HID);
            #pragma unroll
            for (int q = 0; q < 4; ++q) {
                const vfloat4 wv = w4[q];
                acc += s_h[q * 4 + 0] * wv.x + s_h[q * 4 + 1] * wv.y
                     + s_h[q * 4 + 2] * wv.z + s_h[q * 4 + 3] * wv.w;
            }
            outbuf[tid] = acc;
        }
    };

    se_l1(s_desc, sw1, sb1);
    __syncthreads();
    se_l2(sw2, sb2, s_fused);
    __syncthreads();
    se_l1(s_desc + CH, mw1, mb1);
    __syncthreads();
    se_l2(mw2, mb2, s_fused + CH);
    __syncthreads();

    if (tid < 256) {   // bottleneck: g[c] = relu(fused . bw[c,:] + bb[c])
        float acc = bb[tid];
        const vfloat4* wrow = reinterpret_cast<const vfloat4*>(bw + tid * (2 * CH));
        const vfloat4* f4   = reinterpret_cast<const vfloat4*>(s_fused);
        #pragma unroll 8
        for (int q = 0; q < (2 * CH) / 4; ++q) {
            const vfloat4 wv = wrow[q];
            const vfloat4 fv = f4[q];
            acc += fv.x * wv.x + fv.y * wv.y + fv.z * wv.z + fv.w * wv.w;
        }
        s_g[tid] = fmaxf(acc, 0.f);
    }
    __syncthreads();

    se_l1(s_g, fw1, fb1);
    __syncthreads();
    if (tid < 256) {
        float acc = fb2[tid];
        const vfloat4* w4 = reinterpret_cast<const vfloat4*>(fw2 + tid * HID);
        #pragma unroll
        for (int q = 0; q < 4; ++q) {
            const vfloat4 wv = w4[q];
            acc += s_h[q * 4 + 0] * wv.x + s_h[q * 4 + 1] * wv.y
                 + s_h[q * 4 + 2] * wv.z + s_h[q * 4 + 3] * wv.w;
        }
        const float sig = 1.f / (1.f + expf(-acc));
        if ((tid >> 4) == (blockIdx.x & 15))   // this block's 16 channels
            s_mask[tid & 15] = sig;
    }
    __syncthreads();

    // ---------------- Phase 3: scale & store ----------------
    const float mA = s_mask[2 * w];
    const float mB = s_mask[2 * w + 1];
    vfloat4* oA = reinterpret_cast<vfloat4*>(out + (long long)planeA * SPAT);
    vfloat4* oB = reinterpret_cast<vfloat4*>(out + (long long)planeB * SPAT);

    // 1) tail FIRST (exact fp32, L3-hot: only 20.5 MB was read since)
    #pragma unroll
    for (int i = IT_HOLD; i < IT_TOT; ++i) {
        vfloat4 v = pA[lane + i * 64];
        v *= mA;
        __builtin_nontemporal_store(v, &oA[lane + i * 64]);
    }
    #pragma unroll
    for (int i = IT_HOLD; i < IT_TOT; ++i) {
        vfloat4 v = pB[lane + i * 64];
        v *= mB;
        __builtin_nontemporal_store(v, &oB[lane + i * 64]);
    }
    // 2) register-retained bf16
    #pragma unroll
    for (int i = 0; i < IT_REG; ++i) {
        const vfloat4 v = unpack2(rA[2 * i], rA[2 * i + 1], mA);
        __builtin_nontemporal_store(v, &oA[lane + i * 64]);
    }
    #pragma unroll
    for (int i = 0; i < IT_REG; ++i) {
        const vfloat4 v = unpack2(rB[2 * i], rB[2 * i + 1], mB);
        __builtin_nontemporal_store(v, &oB[lane + i * 64]);
    }
    // 3) LDS-retained bf16
    #pragma unroll
    for (int i = 0; i < IT_LDS; ++i) {
        const uint2 u = *reinterpret_cast<const uint2*>(&lds_data[(0 * IT_LDS + i) * 1024 + tid * 2]);
        const vfloat4 v = unpack2(u.x, u.y, mA);
        __builtin_nontemporal_store(v, &oA[lane + (IT_REG + i) * 64]);
    }
    #pragma unroll
    for (int i = 0; i < IT_LDS; ++i) {
        const uint2 u = *reinterpret_cast<const uint2*>(&lds_data[(1 * IT_LDS + i) * 1024 + tid * 2]);
        const vfloat4 v = unpack2(u.x, u.y, mB);
        __builtin_nontemporal_store(v, &oB[lane + (IT_REG + i) * 64]);
    }
}

// ===========================================================================
// Fallback path (R3): 3 plain kernels, used only if cooperative launch fails.
// ===========================================================================
__global__ __launch_bounds__(256) void stats_kernel(const float* __restrict__ x,
                                                    float* __restrict__ mean_g,
                                                    float* __restrict__ std_g)
{
    const long long base = (long long)blockIdx.x * SPAT;
    const vfloat4* x4 = reinterpret_cast<const vfloat4*>(x + base);
    float s = 0.f, s2 = 0.f;
    #pragma unroll
    for (int i = 0; i < 16; ++i) {
        vfloat4 v = x4[threadIdx.x + i * 256];
        s  += v.x + v.y + v.z + v.w;
        s2 += v.x * v.x + v.y * v.y + v.z * v.z + v.w * v.w;
    }
    #pragma unroll
    for (int off = 32; off > 0; off >>= 1) {
        s  += __shfl_xor(s,  off);
        s2 += __shfl_xor(s2, off);
    }
    __shared__ float ws[4], ws2[4];
    const int wave = threadIdx.x >> 6;
    const int lane = threadIdx.x & 63;
    if (lane == 0) { ws[wave] = s; ws2[wave] = s2; }
    __syncthreads();
    if (threadIdx.x == 0) {
        const float ts  = ws[0]  + ws[1]  + ws[2]  + ws[3];
        const float ts2 = ws2[0] + ws2[1] + ws2[2] + ws2[3];
        const float m   = ts * (1.f / SPAT);
        const float var = ts2 * (1.f / SPAT) - m * m;
        mean_g[blockIdx.x] = m;
        std_g[blockIdx.x]  = sqrtf(fmaxf(var, 0.f));
    }
}

__global__ __launch_bounds__(256) void se_chain_kernel(
    const float* __restrict__ mean_g, const float* __restrict__ std_g,
    const float* __restrict__ sw1, const float* __restrict__ sb1,
    const float* __restrict__ sw2, const float* __restrict__ sb2,
    const float* __restrict__ mw1, const float* __restrict__ mb1,
    const float* __restrict__ mw2, const float* __restrict__ mb2,
    const float* __restrict__ bw,  const float* __restrict__ bb,
    const float* __restrict__ fw1, const float* __restrict__ fb1,
    const float* __restrict__ fw2, const float* __restrict__ fb2,
    float* __restrict__ mask_g)
{
    const int b   = blockIdx.x;
    const int tid = threadIdx.x;

    __shared__ float s_desc[2 * CH];
    __shared__ float s_h[HID];
    __shared__ float s_fused[2 * CH];
    __shared__ float s_g[CH];

    s_desc[tid]      = std_g [b * CH + tid];
    s_desc[CH + tid] = mean_g[b * CH + tid];
    __syncthreads();

    auto se_l1 = [&](const float* desc, const float* __restrict__ w1,
                     const float* __restrict__ b1) {
        const int hh = tid >> 4;
        const int j  = tid & 15;
        float acc = 0.f;
        #pragma unroll
        for (int k = 0; k < 16; ++k) {
            const int c = j * 16 + k;
            acc += desc[c] * w1[hh * CH + c];
        }
        #pragma unroll
        for (int off = 1; off < 16; off <<= 1)
            acc += __shfl_xor(acc, off, 16);
        if (j == 0) s_h[hh] = fmaxf(acc + b1[hh], 0.f);
    };
    auto se_l2 = [&](const float* __restrict__ w2, const float* __restrict__ b2,
                     float* outbuf) {
        float acc = b2[tid];
        const vfloat4* w4 = reinterpret_cast<const vfloat4*>(w2 + tid * HID);
        #pragma unroll
        for (int q = 0; q < 4; ++q) {
            const vfloat4 wv = w4[q];
            acc += s_h[q * 4 + 0] * wv.x + s_h[q * 4 + 1] * wv.y
                 + s_h[q * 4 + 2] * wv.z + s_h[q * 4 + 3] * wv.w;
        }
        outbuf[tid] = acc;
    };

    se_l1(s_desc, sw1, sb1);
    __syncthreads();
    se_l2(sw2, sb2, s_fused);
    __syncthreads();
    se_l1(s_desc + CH, mw1, mb1);
    __syncthreads();
    se_l2(mw2, mb2, s_fused + CH);
    __syncthreads();
    {
        float acc = bb[tid];
        const vfloat4* wrow = reinterpret_cast<const vfloat4*>(bw + tid * (2 * CH));
        const vfloat4* f4   = reinterpret_cast<const vfloat4*>(s_fused);
        #pragma unroll 8
        for (int q = 0; q < (2 * CH) / 4; ++q) {
            const vfloat4 wv = wrow[q];
            const vfloat4 fv = f4[q];
            acc += fv.x * wv.x + fv.y * wv.y + fv.z * wv.z + fv.w * wv.w;
        }
        s_g[tid] = fmaxf(acc, 0.f);
    }
    __syncthreads();
    se_l1(s_g, fw1, fb1);
    __syncthreads();
    {
        float acc = fb2[tid];
        const vfloat4* w4 = reinterpret_cast<const vfloat4*>(fw2 + tid * HID);
        #pragma unroll
        for (int q = 0; q < 4; ++q) {
            const vfloat4 wv = w4[q];
            acc += s_h[q * 4 + 0] * wv.x + s_h[q * 4 + 1] * wv.y
                 + s_h[q * 4 + 2] * wv.z + s_h[q * 4 + 3] * wv.w;
        }
        mask_g[b * CH + tid] = 1.f / (1.f + expf(-acc));
    }
}

__global__ __launch_bounds__(256) void scale_kernel(const float* __restrict__ x,
                                                    const float* __restrict__ mask,
                                                    float* __restrict__ out)
{
    const int plane = (NPLANE - 1) - blockIdx.x;
    const float m = mask[plane];
    const long long base = (long long)plane * SPAT;
    const vfloat4* x4 = reinterpret_cast<const vfloat4*>(x + base);
    vfloat4*       o4 = reinterpret_cast<vfloat4*>(out + base);
    #pragma unroll
    for (int i = 0; i < 16; ++i) {
        vfloat4 v = x4[threadIdx.x + i * 256];
        v *= m;
        __builtin_nontemporal_store(v, &o4[threadIdx.x + i * 256]);
    }
}

// ---------------------------------------------------------------------------
extern "C" void kernel_launch(void* const* d_in, const int* in_sizes, int n_in,
                              void* d_out, int out_size, void* d_ws, size_t ws_size,
                              hipStream_t stream)
{
    const float* x   = (const float*)d_in[0];
    const float* sw1 = (const float*)d_in[1];
    const float* sb1 = (const float*)d_in[2];
    const float* sw2 = (const float*)d_in[3];
    const float* sb2 = (const float*)d_in[4];
    const float* mw1 = (const float*)d_in[5];
    const float* mb1 = (const float*)d_in[6];
    const float* mw2 = (const float*)d_in[7];
    const float* mb2 = (const float*)d_in[8];
    const float* bw  = (const float*)d_in[9];
    const float* bb  = (const float*)d_in[10];
    const float* fw1 = (const float*)d_in[11];
    const float* fb1 = (const float*)d_in[12];
    const float* fw2 = (const float*)d_in[13];
    const float* fb2 = (const float*)d_in[14];

    float* out = (float*)d_out;

    float* mean_g = (float*)d_ws;
    float* std_g  = mean_g + NPLANE;
    float* mask_g = std_g  + NPLANE;   // fallback path only

    void* args[] = {
        (void*)&x,
        (void*)&sw1, (void*)&sb1, (void*)&sw2, (void*)&sb2,
        (void*)&mw1, (void*)&mb1, (void*)&mw2, (void*)&mb2,
        (void*)&bw,  (void*)&bb,
        (void*)&fw1, (void*)&fb1, (void*)&fw2, (void*)&fb2,
        (void*)&out, (void*)&mean_g, (void*)&std_g
    };

    hipError_t err = hipLaunchCooperativeKernel(
        (const void*)coop_kernel, dim3(256), dim3(512), args, 0, stream);

    if (err != hipSuccess) {
        // Fallback: R3 three-kernel path.
        stats_kernel<<<NPLANE, 256, 0, stream>>>(x, mean_g, std_g);
        se_chain_kernel<<<BATCH, 256, 0, stream>>>(mean_g, std_g,
                                                   sw1, sb1, sw2, sb2,
                                                   mw1, mb1, mw2, mb2,
                                                   bw, bb,
                                                   fw1, fb1, fw2, fb2,
                                                   mask_g);
        scale_kernel<<<NPLANE, 256, 0, stream>>>(x, mask_g, out);
    }
}

// Round 10
// 266.247 us; speedup vs baseline: 1.1207x; 1.1207x over previous
//
#include <hip/hip_runtime.h>
#include <hip/hip_cooperative_groups.h>
#include <math.h>

// Problem geometry (fixed by reference):
//   x: [B=16, C=256, 128, 128] fp32 ; H = 16 ; spatial N = 16384
#define BATCH 16
#define CH    256
#define HID   16
#define SPAT  16384            // 128*128
#define NPLANE (BATCH * CH)    // 4096 planes, 64 KiB fp32 each

typedef float vfloat4 __attribute__((ext_vector_type(4)));

// 256 blocks x 256 threads (4 waves = 1 wave/SIMD at 1 block/CU -> VGPR cap
// ~512, register pressure sets allocation). Each wave owns 4 planes; each
// plane is 64 float4-iters per lane:
//   iters 0..37  -> registers (38*2 dwords * 4 planes = 304 dwords/thread)
//   iters 38..56 -> LDS       (19 iters * 2 dwords * 64 ln * 16 wave-planes = 155,648 B)
//   iters 57..63 -> tail, re-read in phase 3 (29 MB total, L3-hot)
#define IT_REG  38
#define IT_LDS  19
#define IT_HOLD (IT_REG + IT_LDS)   // 57
#define IT_TOT  64

namespace cg = cooperative_groups;

// bf16 round-to-nearest-even, plain integer ops (finite inputs only)
__device__ __forceinline__ unsigned short f2bf(float f) {
    unsigned int u = __builtin_bit_cast(unsigned int, f);
    u += 0x7fffu + ((u >> 16) & 1u);
    return (unsigned short)(u >> 16);
}
__device__ __forceinline__ float bf2f(unsigned short h) {
    unsigned int u = ((unsigned int)h) << 16;
    return __builtin_bit_cast(float, u);
}
__device__ __forceinline__ unsigned pack_bf2(float a, float b) {
    return (unsigned)f2bf(a) | ((unsigned)f2bf(b) << 16);
}
__device__ __forceinline__ vfloat4 unpack2(unsigned u0, unsigned u1, float m) {
    vfloat4 v;
    v.x = bf2f((unsigned short)(u0 & 0xffffu)) * m;
    v.y = bf2f((unsigned short)(u0 >> 16))     * m;
    v.z = bf2f((unsigned short)(u1 & 0xffffu)) * m;
    v.w = bf2f((unsigned short)(u1 >> 16))     * m;
    return v;
}

// ---------------------------------------------------------------------------
// Cooperative persistent kernel: 256 blocks x 256 threads, 1 block/CU.
// Bare __launch_bounds__(256): no occupancy request -> register pressure
// (not an occupancy target) sets VGPR allocation. R6-R9 showed any >=512
// thread block got capped at <=128 VGPR and spilled the retention array.
// ---------------------------------------------------------------------------
__global__ __launch_bounds__(256) void coop_kernel(
    const float* __restrict__ x,
    const float* __restrict__ sw1, const float* __restrict__ sb1,
    const float* __restrict__ sw2, const float* __restrict__ sb2,
    const float* __restrict__ mw1, const float* __restrict__ mb1,
    const float* __restrict__ mw2, const float* __restrict__ mb2,
    const float* __restrict__ bw,  const float* __restrict__ bb,
    const float* __restrict__ fw1, const float* __restrict__ fb1,
    const float* __restrict__ fw2, const float* __restrict__ fb2,
    float* __restrict__ out,
    float* __restrict__ mean_g, float* __restrict__ std_g)
{
    __shared__ unsigned lds_data[16 * IT_LDS * 128];  // 155,648 B retained bf16
    __shared__ float s_desc[2 * CH];                  // SE scratch (5,248 B)
    __shared__ float s_h[HID];
    __shared__ float s_fused[2 * CH];
    __shared__ float s_g[CH];
    __shared__ float s_mask[16];

    const int tid  = threadIdx.x;
    const int w    = tid >> 6;          // wave 0..3
    const int lane = tid & 63;
    const int planeBase = blockIdx.x * 16 + w * 4;    // this wave's 4 planes

    unsigned r0[2 * IT_REG], r1[2 * IT_REG], r2[2 * IT_REG], r3[2 * IT_REG];

    // ---------------- Phase 1: stats + bf16 retention ----------------
    // Retained iters: NON-TEMPORAL loads (keep L3 clean). Tail iters: CACHED
    // loads, read LAST -> L3-hot when phase 3 re-reads them first.
#define PROC_PLANE(P, R)                                                        \
    {                                                                           \
        const vfloat4* pp = reinterpret_cast<const vfloat4*>(                   \
            x + (long long)(planeBase + (P)) * SPAT);                           \
        float s = 0.f, s2 = 0.f;                                                \
        _Pragma("unroll") for (int i = 0; i < IT_REG; ++i) {                    \
            const vfloat4 v = __builtin_nontemporal_load(&pp[lane + i * 64]);   \
            s  += (v.x + v.y) + (v.z + v.w);                                    \
            s2  = fmaf(v.x, v.x, fmaf(v.y, v.y,                                 \
                    fmaf(v.z, v.z, fmaf(v.w, v.w, s2))));                       \
            R[2 * i]     = pack_bf2(v.x, v.y);                                  \
            R[2 * i + 1] = pack_bf2(v.z, v.w);                                  \
        }                                                                       \
        _Pragma("unroll") for (int i = 0; i < IT_LDS; ++i) {                    \
            const vfloat4 v =                                                   \
                __builtin_nontemporal_load(&pp[lane + (IT_REG + i) * 64]);      \
            s  += (v.x + v.y) + (v.z + v.w);                                    \
            s2  = fmaf(v.x, v.x, fmaf(v.y, v.y,                                 \
                    fmaf(v.z, v.z, fmaf(v.w, v.w, s2))));                       \
            uint2 u; u.x = pack_bf2(v.x, v.y); u.y = pack_bf2(v.z, v.w);        \
            *reinterpret_cast<uint2*>(                                          \
                &lds_data[((w * 4 + (P)) * IT_LDS + i) * 128 + lane * 2]) = u;  \
        }                                                                       \
        _Pragma("unroll") for (int i = IT_HOLD; i < IT_TOT; ++i) {              \
            const vfloat4 v = pp[lane + i * 64];                                \
            s  += (v.x + v.y) + (v.z + v.w);                                    \
            s2  = fmaf(v.x, v.x, fmaf(v.y, v.y,                                 \
                    fmaf(v.z, v.z, fmaf(v.w, v.w, s2))));                       \
        }                                                                       \
        _Pragma("unroll") for (int off = 32; off > 0; off >>= 1) {              \
            s  += __shfl_xor(s,  off);                                          \
            s2 += __shfl_xor(s2, off);                                          \
        }                                                                       \
        if (lane == 0) {                                                        \
            const float mm  = s * (1.f / SPAT);                                 \
            const float var = s2 * (1.f / SPAT) - mm * mm;                      \
            mean_g[planeBase + (P)] = mm;                                       \
            std_g [planeBase + (P)] = sqrtf(fmaxf(var, 0.f));                   \
        }                                                                       \
    }

    PROC_PLANE(0, r0)
    PROC_PLANE(1, r1)
    PROC_PLANE(2, r2)
    PROC_PLANE(3, r3)
#undef PROC_PLANE

    cg::this_grid().sync();

    // ---------------- Phase 2: SE chain for this block's batch row ----------
    const int brow = blockIdx.x >> 4;     // 16 blocks share a batch row
    s_desc[tid]      = std_g [brow * CH + tid];
    s_desc[CH + tid] = mean_g[brow * CH + tid];
    __syncthreads();

    auto se_l1 = [&](const float* desc, const float* __restrict__ w1,
                     const float* __restrict__ b1) {
        const int hh = tid >> 4;
        const int j  = tid & 15;
        float acc = 0.f;
        #pragma unroll
        for (int k = 0; k < 16; ++k) {
            const int c = j * 16 + k;
            acc += desc[c] * w1[hh * CH + c];
        }
        #pragma unroll
        for (int off = 1; off < 16; off <<= 1)
            acc += __shfl_xor(acc, off, 16);
        if (j == 0) s_h[hh] = fmaxf(acc + b1[hh], 0.f);
    };
    auto se_l2 = [&](const float* __restrict__ w2, const float* __restrict__ b2,
                     float* outbuf) {
        float acc = b2[tid];
        const vfloat4* w4 = reinterpret_cast<const vfloat4*>(w2 + tid * HID);
        #pragma unroll
        for (int q = 0; q < 4; ++q) {
            const vfloat4 wv = w4[q];
            acc += s_h[q * 4 + 0] * wv.x + s_h[q * 4 + 1] * wv.y
                 + s_h[q * 4 + 2] * wv.z + s_h[q * 4 + 3] * wv.w;
        }
        outbuf[tid] = acc;
    };

    se_l1(s_desc, sw1, sb1);
    __syncthreads();
    se_l2(sw2, sb2, s_fused);
    __syncthreads();
    se_l1(s_desc + CH, mw1, mb1);
    __syncthreads();
    se_l2(mw2, mb2, s_fused + CH);
    __syncthreads();

    {   // bottleneck: g[c] = relu(fused . bw[c,:] + bb[c])
        float acc = bb[tid];
        const vfloat4* wrow = reinterpret_cast<const vfloat4*>(bw + tid * (2 * CH));
        const vfloat4* f4   = reinterpret_cast<const vfloat4*>(s_fused);
        #pragma unroll 8
        for (int q = 0; q < (2 * CH) / 4; ++q) {
            const vfloat4 wv = wrow[q];
            const vfloat4 fv = f4[q];
            acc += fv.x * wv.x + fv.y * wv.y + fv.z * wv.z + fv.w * wv.w;
        }
        s_g[tid] = fmaxf(acc, 0.f);
    }
    __syncthreads();

    se_l1(s_g, fw1, fb1);
    __syncthreads();
    {
        float acc = fb2[tid];
        const vfloat4* w4 = reinterpret_cast<const vfloat4*>(fw2 + tid * HID);
        #pragma unroll
        for (int q = 0; q < 4; ++q) {
            const vfloat4 wv = w4[q];
            acc += s_h[q * 4 + 0] * wv.x + s_h[q * 4 + 1] * wv.y
                 + s_h[q * 4 + 2] * wv.z + s_h[q * 4 + 3] * wv.w;
        }
        const float sig = 1.f / (1.f + expf(-acc));
        if ((tid >> 4) == (blockIdx.x & 15))   // this block's 16 channels
            s_mask[tid & 15] = sig;
    }
    __syncthreads();

    // ---------------- Phase 3: scale & store ----------------
    // Tail re-read FIRST (exact fp32, L3-hot), then registers, then LDS.
#define TAIL_PLANE(P)                                                           \
    {                                                                           \
        const float m = s_mask[w * 4 + (P)];                                    \
        const vfloat4* pp = reinterpret_cast<const vfloat4*>(                   \
            x + (long long)(planeBase + (P)) * SPAT);                           \
        vfloat4* oo = reinterpret_cast<vfloat4*>(                               \
            out + (long long)(planeBase + (P)) * SPAT);                         \
        _Pragma("unroll") for (int i = IT_HOLD; i < IT_TOT; ++i) {              \
            vfloat4 v = pp[lane + i * 64];                                      \
            v *= m;                                                             \
            __builtin_nontemporal_store(v, &oo[lane + i * 64]);                 \
        }                                                                       \
    }
#define REG_PLANE(P, R)                                                         \
    {                                                                           \
        const float m = s_mask[w * 4 + (P)];                                    \
        vfloat4* oo = reinterpret_cast<vfloat4*>(                               \
            out + (long long)(planeBase + (P)) * SPAT);                         \
        _Pragma("unroll") for (int i = 0; i < IT_REG; ++i) {                    \
            const vfloat4 v = unpack2(R[2 * i], R[2 * i + 1], m);               \
            __builtin_nontemporal_store(v, &oo[lane + i * 64]);                 \
        }                                                                       \
    }
#define LDSST_PLANE(P)                                                          \
    {                                                                           \
        const float m = s_mask[w * 4 + (P)];                                    \
        vfloat4* oo = reinterpret_cast<vfloat4*>(                               \
            out + (long long)(planeBase + (P)) * SPAT);                         \
        _Pragma("unroll") for (int i = 0; i < IT_LDS; ++i) {                    \
            const uint2 u = *reinterpret_cast<const uint2*>(                    \
                &lds_data[((w * 4 + (P)) * IT_LDS + i) * 128 + lane * 2]);      \
            const vfloat4 v = unpack2(u.x, u.y, m);                             \
            __builtin_nontemporal_store(v, &oo[lane + (IT_REG + i) * 64]);      \
        }                                                                       \
    }

    TAIL_PLANE(0)
    TAIL_PLANE(1)
    TAIL_PLANE(2)
    TAIL_PLANE(3)
    REG_PLANE(0, r0)
    REG_PLANE(1, r1)
    REG_PLANE(2, r2)
    REG_PLANE(3, r3)
    LDSST_PLANE(0)
    LDSST_PLANE(1)
    LDSST_PLANE(2)
    LDSST_PLANE(3)
#undef TAIL_PLANE
#undef REG_PLANE
#undef LDSST_PLANE
}

// ===========================================================================
// Fallback path (R3): 3 plain kernels, used only if cooperative launch fails.
// ===========================================================================
__global__ __launch_bounds__(256) void stats_kernel(const float* __restrict__ x,
                                                    float* __restrict__ mean_g,
                                                    float* __restrict__ std_g)
{
    const long long base = (long long)blockIdx.x * SPAT;
    const vfloat4* x4 = reinterpret_cast<const vfloat4*>(x + base);
    float s = 0.f, s2 = 0.f;
    #pragma unroll
    for (int i = 0; i < 16; ++i) {
        vfloat4 v = x4[threadIdx.x + i * 256];
        s  += v.x + v.y + v.z + v.w;
        s2 += v.x * v.x + v.y * v.y + v.z * v.z + v.w * v.w;
    }
    #pragma unroll
    for (int off = 32; off > 0; off >>= 1) {
        s  += __shfl_xor(s,  off);
        s2 += __shfl_xor(s2, off);
    }
    __shared__ float ws[4], ws2[4];
    const int wave = threadIdx.x >> 6;
    const int lane = threadIdx.x & 63;
    if (lane == 0) { ws[wave] = s; ws2[wave] = s2; }
    __syncthreads();
    if (threadIdx.x == 0) {
        const float ts  = ws[0]  + ws[1]  + ws[2]  + ws[3];
        const float ts2 = ws2[0] + ws2[1] + ws2[2] + ws2[3];
        const float m   = ts * (1.f / SPAT);
        const float var = ts2 * (1.f / SPAT) - m * m;
        mean_g[blockIdx.x] = m;
        std_g[blockIdx.x]  = sqrtf(fmaxf(var, 0.f));
    }
}

__global__ __launch_bounds__(256) void se_chain_kernel(
    const float* __restrict__ mean_g, const float* __restrict__ std_g,
    const float* __restrict__ sw1, const float* __restrict__ sb1,
    const float* __restrict__ sw2, const float* __restrict__ sb2,
    const float* __restrict__ mw1, const float* __restrict__ mb1,
    const float* __restrict__ mw2, const float* __restrict__ mb2,
    const float* __restrict__ bw,  const float* __restrict__ bb,
    const float* __restrict__ fw1, const float* __restrict__ fb1,
    const float* __restrict__ fw2, const float* __restrict__ fb2,
    float* __restrict__ mask_g)
{
    const int b   = blockIdx.x;
    const int tid = threadIdx.x;

    __shared__ float s_desc[2 * CH];
    __shared__ float s_h[HID];
    __shared__ float s_fused[2 * CH];
    __shared__ float s_g[CH];

    s_desc[tid]      = std_g [b * CH + tid];
    s_desc[CH + tid] = mean_g[b * CH + tid];
    __syncthreads();

    auto se_l1 = [&](const float* desc, const float* __restrict__ w1,
                     const float* __restrict__ b1) {
        const int hh = tid >> 4;
        const int j  = tid & 15;
        float acc = 0.f;
        #pragma unroll
        for (int k = 0; k < 16; ++k) {
            const int c = j * 16 + k;
            acc += desc[c] * w1[hh * CH + c];
        }
        #pragma unroll
        for (int off = 1; off < 16; off <<= 1)
            acc += __shfl_xor(acc, off, 16);
        if (j == 0) s_h[hh] = fmaxf(acc + b1[hh], 0.f);
    };
    auto se_l2 = [&](const float* __restrict__ w2, const float* __restrict__ b2,
                     float* outbuf) {
        float acc = b2[tid];
        const vfloat4* w4 = reinterpret_cast<const vfloat4*>(w2 + tid * HID);
        #pragma unroll
        for (int q = 0; q < 4; ++q) {
            const vfloat4 wv = w4[q];
            acc += s_h[q * 4 + 0] * wv.x + s_h[q * 4 + 1] * wv.y
                 + s_h[q * 4 + 2] * wv.z + s_h[q * 4 + 3] * wv.w;
        }
        outbuf[tid] = acc;
    };

    se_l1(s_desc, sw1, sb1);
    __syncthreads();
    se_l2(sw2, sb2, s_fused);
    __syncthreads();
    se_l1(s_desc + CH, mw1, mb1);
    __syncthreads();
    se_l2(mw2, mb2, s_fused + CH);
    __syncthreads();
    {
        float acc = bb[tid];
        const vfloat4* wrow = reinterpret_cast<const vfloat4*>(bw + tid * (2 * CH));
        const vfloat4* f4   = reinterpret_cast<const vfloat4*>(s_fused);
        #pragma unroll 8
        for (int q = 0; q < (2 * CH) / 4; ++q) {
            const vfloat4 wv = wrow[q];
            const vfloat4 fv = f4[q];
            acc += fv.x * wv.x + fv.y * wv.y + fv.z * wv.z + fv.w * wv.w;
        }
        s_g[tid] = fmaxf(acc, 0.f);
    }
    __syncthreads();
    se_l1(s_g, fw1, fb1);
    __syncthreads();
    {
        float acc = fb2[tid];
        const vfloat4* w4 = reinterpret_cast<const vfloat4*>(fw2 + tid * HID);
        #pragma unroll
        for (int q = 0; q < 4; ++q) {
            const vfloat4 wv = w4[q];
            acc += s_h[q * 4 + 0] * wv.x + s_h[q * 4 + 1] * wv.y
                 + s_h[q * 4 + 2] * wv.z + s_h[q * 4 + 3] * wv.w;
        }
        mask_g[b * CH + tid] = 1.f / (1.f + expf(-acc));
    }
}

__global__ __launch_bounds__(256) void scale_kernel(const float* __restrict__ x,
                                                    const float* __restrict__ mask,
                                                    float* __restrict__ out)
{
    const int plane = (NPLANE - 1) - blockIdx.x;
    const float m = mask[plane];
    const long long base = (long long)plane * SPAT;
    const vfloat4* x4 = reinterpret_cast<const vfloat4*>(x + base);
    vfloat4*       o4 = reinterpret_cast<vfloat4*>(out + base);
    #pragma unroll
    for (int i = 0; i < 16; ++i) {
        vfloat4 v = x4[threadIdx.x + i * 256];
        v *= m;
        __builtin_nontemporal_store(v, &o4[threadIdx.x + i * 256]);
    }
}

// ---------------------------------------------------------------------------
extern "C" void kernel_launch(void* const* d_in, const int* in_sizes, int n_in,
                              void* d_out, int out_size, void* d_ws, size_t ws_size,
                              hipStream_t stream)
{
    const float* x   = (const float*)d_in[0];
    const float* sw1 = (const float*)d_in[1];
    const float* sb1 = (const float*)d_in[2];
    const float* sw2 = (const float*)d_in[3];
    const float* sb2 = (const float*)d_in[4];
    const float* mw1 = (const float*)d_in[5];
    const float* mb1 = (const float*)d_in[6];
    const float* mw2 = (const float*)d_in[7];
    const float* mb2 = (const float*)d_in[8];
    const float* bw  = (const float*)d_in[9];
    const float* bb  = (const float*)d_in[10];
    const float* fw1 = (const float*)d_in[11];
    const float* fb1 = (const float*)d_in[12];
    const float* fw2 = (const float*)d_in[13];
    const float* fb2 = (const float*)d_in[14];

    float* out = (float*)d_out;

    float* mean_g = (float*)d_ws;
    float* std_g  = mean_g + NPLANE;
    float* mask_g = std_g  + NPLANE;   // fallback path only

    void* args[] = {
        (void*)&x,
        (void*)&sw1, (void*)&sb1, (void*)&sw2, (void*)&sb2,
        (void*)&mw1, (void*)&mb1, (void*)&mw2, (void*)&mb2,
        (void*)&bw,  (void*)&bb,
        (void*)&fw1, (void*)&fb1, (void*)&fw2, (void*)&fb2,
        (void*)&out, (void*)&mean_g, (void*)&std_g
    };

    hipError_t err = hipLaunchCooperativeKernel(
        (const void*)coop_kernel, dim3(256), dim3(256), args, 0, stream);

    if (err != hipSuccess) {
        // Fallback: R3 three-kernel path.
        stats_kernel<<<NPLANE, 256, 0, stream>>>(x, mean_g, std_g);
        se_chain_kernel<<<BATCH, 256, 0, stream>>>(mean_g, std_g,
                                                   sw1, sb1, sw2, sb2,
                                                   mw1, mb1, mw2, mb2,
                                                   bw, bb,
                                                   fw1, fb1, fw2, fb2,
                                                   mask_g);
        scale_kernel<<<NPLANE, 256, 0, stream>>>(x, mask_g, out);
    }
}